// Round 10
// baseline (238.280 us; speedup 1.0000x reference)
//
#include <hip/hip_runtime.h>
#include <math.h>

#define HOUT 48
#define WOUT 320
#define NB   8
#define NBOX 64
#define NC   3
#define IMH  1024
#define IMW  1024

#define PIX_PER_CROP (HOUT * WOUT)            // 15360
#define BLK 256
#define TILES_Y (HOUT / 16)                   // 3
#define TILES_X (WOUT / 16)                   // 20
#define BLKS_PER_CROP (TILES_Y * TILES_X)     // 60
#define NBLOCKS (NB * NBOX * BLKS_PER_CROP)   // 30720

// Staged source bbox per 16x16 output tile.
// Max source extent per axis: sqrt((15*300/320)^2 + (15*60/48)^2) = 23.4 px
// -> floor-span 24 +1 bilinear tap +1 fp margin each side => 28 covers it.
#define LROWS 28
#define LCOLS 28
#define LN (NC * LROWS * LCOLS)               // 2352 floats = 9408 B LDS
#define NITER ((LN + BLK - 1) / BLK)          // 10

__global__ __launch_bounds__(BLK) void rot_crop_kernel(
    const float* __restrict__ x,      // [NB, NC, IMH, IMW]
    const float* __restrict__ boxes,  // [NB, NBOX, 5]
    float* __restrict__ out)          // [NB*NBOX, NC, HOUT, WOUT]
{
    __shared__ float smem[NC][LROWS][LCOLS];

    // XCD-aware bijective swizzle (NBLOCKS % 8 == 0).
    const int bid = (blockIdx.x & 7) * (NBLOCKS / 8) + (blockIdx.x >> 3);

    const int bn = bid / BLKS_PER_CROP;            // crop index [0, 512)
    const int t  = bid % BLKS_PER_CROP;
    const int bi = t / TILES_X;                    // tile row [0, 3)
    const int bj = t % TILES_X;                    // tile col [0, 20)

    const int lane = threadIdx.x & 63;
    const int wv   = threadIdx.x >> 6;             // 0..3
    const int i = bi * 16 + wv * 4 + (lane >> 4);  // output row
    const int j = bj * 16 + (lane & 15);           // output col
    const int b = bn / NBOX;                       // batch image

    // Box params — block-uniform -> scalar loads.
    const float* box = boxes + bn * 5;
    const float cx  = box[0];
    const float cy  = box[1];
    const float bw  = box[2];
    const float bh  = box[3];
    const float ang = box[4];

    const float theta = ang * (-3.14159265358979323846f / 180.0f);
    float st, ct;
    __sincosf(theta, &st, &ct);
    const float bb = ct * 0.5f;
    const float aa = st * 0.5f;

    const float p0x = cx - aa * bh - bb * bw;
    const float p0y = cy + bb * bh - aa * bw;
    const float p1x = cx + aa * bh - bb * bw;
    const float p1y = cy - bb * bh - aa * bw;
    const float p2x = 2.0f * cx - p0x;
    const float p2y = 2.0f * cy - p0y;

    const float ax = p2x - p1x;   // d(source)/du * 1
    const float ay = p2y - p1y;
    const float bx_ = p0x - p1x;  // d(source)/dv * 1
    const float by_ = p0y - p1y;

    // Block-uniform source bbox (affine => extrema at tile corners).
    const float u0 = (float)(bj * 16)      * (1.0f / WOUT);
    const float u1 = (float)(bj * 16 + 15) * (1.0f / WOUT);
    const float v0 = (float)(bi * 16)      * (1.0f / HOUT);
    const float v1 = (float)(bi * 16 + 15) * (1.0f / HOUT);
    const float xminf = p1x + fminf(u0 * ax, u1 * ax) + fminf(v0 * bx_, v1 * bx_);
    const float yminf = p1y + fminf(u0 * ay, u1 * ay) + fminf(v0 * by_, v1 * by_);
    const int x_lo = (int)floorf(xminf) - 1;   // -1 fp margin
    const int y_lo = (int)floorf(yminf) - 1;

    // Stage bbox into LDS; out-of-image texels staged as 0 — this IS the
    // reference's zero-padding, so the bilinear needs no validity masks.
    const float* img = x + (long long)b * NC * IMH * IMW;
#pragma unroll
    for (int k = 0; k < NITER; ++k) {
        const int f = (int)threadIdx.x + k * BLK;
        if (f < LN) {
            const int c   = f / (LROWS * LCOLS);
            const int rem = f - c * (LROWS * LCOLS);
            const int r   = rem / LCOLS;
            const int col = rem - r * LCOLS;
            const int gr = y_lo + r;
            const int gc = x_lo + col;
            float val = 0.0f;
            if (((unsigned)gr < IMH) & ((unsigned)gc < IMW))
                val = img[c * (IMH * IMW) + gr * IMW + gc];
            (&smem[0][0][0])[f] = val;
        }
    }
    __syncthreads();

    // Bilinear sample from LDS.
    const float u = (float)j * (1.0f / WOUT);
    const float v = (float)i * (1.0f / HOUT);
    const float sx = p1x + u * ax + v * bx_;
    const float sy = p1y + u * ay + v * by_;

    const float x0f = floorf(sx);
    const float y0f = floorf(sy);
    const float dx = sx - x0f;
    const float dy = sy - y0f;

    // LDS-local tap coords; clamp is a no-op except under fp ulp pathology
    // (guarded by the ±1 bbox margin) — prevents OOB LDS access.
    const int lx = min(max((int)x0f - x_lo, 0), LCOLS - 2);
    const int ly = min(max((int)y0f - y_lo, 0), LROWS - 2);

    const float w00 = (1.0f - dx) * (1.0f - dy);
    const float w10 = dx * (1.0f - dy);
    const float w01 = (1.0f - dx) * dy;
    const float w11 = dx * dy;

    float* op = out + (long long)bn * NC * PIX_PER_CROP + i * WOUT + j;
#pragma unroll
    for (int c = 0; c < NC; ++c) {
        const float* s0 = &smem[c][ly][lx];
        const float acc = s0[0] * w00 + s0[1] * w10
                        + s0[LCOLS] * w01 + s0[LCOLS + 1] * w11;
        op[c * PIX_PER_CROP] = acc;
    }
}

extern "C" void kernel_launch(void* const* d_in, const int* in_sizes, int n_in,
                              void* d_out, int out_size, void* d_ws, size_t ws_size,
                              hipStream_t stream) {
    const float* x     = (const float*)d_in[0];
    const float* boxes = (const float*)d_in[1];
    float* out         = (float*)d_out;

    rot_crop_kernel<<<NBLOCKS, BLK, 0, stream>>>(x, boxes, out);
}

// Round 11
// 187.852 us; speedup vs baseline: 1.2684x; 1.2684x over previous
//
#include <hip/hip_runtime.h>
#include <math.h>

#define HOUT 48
#define WOUT 320
#define NB   8
#define NBOX 64
#define NC   3
#define IMH  1024
#define IMW  1024

#define PIX_PER_CROP (HOUT * WOUT)            // 15360
#define BLK 256
#define TILES_Y (HOUT / 16)                   // 3 (16 output rows per block)
#define TILES_X (WOUT / 32)                   // 10 (32 output cols per block)
#define BLKS_PER_CROP (TILES_Y * TILES_X)     // 30
#define NBLOCKS (NB * NBOX * BLKS_PER_CROP)   // 15360

// 16B window with only 4B alignment guarantee -> compiler emits dwordx4.
struct __attribute__((packed, aligned(4))) F4 { float v0, v1, v2, v3; };
// Output pair: address is always 8B-aligned (j even, WOUT/PIX_PER_CROP even).
struct __attribute__((aligned(8))) F2o { float a, b; };

__global__ __launch_bounds__(BLK) void rot_crop_kernel(
    const float* __restrict__ x,      // [NB, NC, IMH, IMW]
    const float* __restrict__ boxes,  // [NB, NBOX, 5]
    float* __restrict__ out)          // [NB*NBOX, NC, HOUT, WOUT]
{
    // XCD-aware bijective swizzle (NBLOCKS % 8 == 0).
    const int bid = (blockIdx.x & 7) * (NBLOCKS / 8) + (blockIdx.x >> 3);

    const int bn = bid / BLKS_PER_CROP;            // crop index [0, 512)
    const int t  = bid % BLKS_PER_CROP;
    const int bi = t / TILES_X;                    // tile row [0, 3)
    const int bj = t % TILES_X;                    // tile col [0, 10)

    // Wave tile: 4 output rows x 32 cols; each lane owns a horizontal px pair.
    const int lane = threadIdx.x & 63;
    const int wv   = threadIdx.x >> 6;             // 0..3
    const int i  = bi * 16 + wv * 4 + (lane >> 4); // output row
    const int j0 = bj * 32 + (lane & 15) * 2;      // even output col (pair base)
    const int b = bn / NBOX;                       // batch image

    // Box params — block-uniform -> scalar loads.
    const float* box = boxes + bn * 5;
    const float cx  = box[0];
    const float cy  = box[1];
    const float bw  = box[2];
    const float bh  = box[3];
    const float ang = box[4];

    const float theta = ang * (-3.14159265358979323846f / 180.0f);
    float st, ct;
    __sincosf(theta, &st, &ct);
    const float bb = ct * 0.5f;
    const float aa = st * 0.5f;

    const float p0x = cx - aa * bh - bb * bw;
    const float p0y = cy + bb * bh - aa * bw;
    const float p1x = cx + aa * bh - bb * bw;
    const float p1y = cy - bb * bh - aa * bw;
    const float p2x = 2.0f * cx - p0x;
    const float p2y = 2.0f * cy - p0y;

    const float ax  = p2x - p1x;   // = bw*cos(theta) > 0, < 320
    const float ay  = p2y - p1y;   // = bw*sin(theta), |ay|/320 <= 0.67
    const float bx_ = p0x - p1x;
    const float by_ = p0y - p1y;

    const float u0 = (float)j0 * (1.0f / WOUT);
    const float u1 = (float)(j0 + 1) * (1.0f / WOUT);
    const float v  = (float)i * (1.0f / HOUT);

    const float sxA = p1x + u0 * ax + v * bx_;
    const float sxB = p1x + u1 * ax + v * bx_;
    const float syA = p1y + u0 * ay + v * by_;
    const float syB = p1y + u1 * ay + v * by_;

    // px A
    const float fxA = floorf(sxA), fyA = floorf(syA);
    const float dxA = sxA - fxA,  dyA = syA - fyA;
    const int   XA = (int)fxA,    YA = (int)fyA;
    // px B (sxB >= sxA since ax>0 and rounding is monotone; XB-XA in {0,1})
    const float fxB = floorf(sxB), fyB = floorf(syB);
    const float dxB = sxB - fxB,  dyB = syB - fyB;
    const int   XB = (int)fxB,    YB = (int)fyB;

    // One 4-texel x-window covers both pixels' taps (valid taps in [XA, XA+2]).
    const int base = min(max(XA, 0), IMW - 4);

    // Branch-free slot weights over the 4-texel window, validity folded in.
    const int sA = XA - base;
    const float wxA0 = (1.0f - dxA) * (float)((unsigned)XA < IMW);
    const float wxA1 = dxA          * (float)((unsigned)(XA + 1) < IMW);
    const float wA0 = (sA == 0 ? wxA0 : 0.0f) + (sA == -1 ? wxA1 : 0.0f);
    const float wA1 = (sA == 1 ? wxA0 : 0.0f) + (sA ==  0 ? wxA1 : 0.0f);
    const float wA2 = (sA == 2 ? wxA0 : 0.0f) + (sA ==  1 ? wxA1 : 0.0f);
    const float wA3 = (sA == 3 ? wxA0 : 0.0f) + (sA ==  2 ? wxA1 : 0.0f);

    const int sB = XB - base;
    const float wxB0 = (1.0f - dxB) * (float)((unsigned)XB < IMW);
    const float wxB1 = dxB          * (float)((unsigned)(XB + 1) < IMW);
    const float wB0 = (sB == 0 ? wxB0 : 0.0f) + (sB == -1 ? wxB1 : 0.0f);
    const float wB1 = (sB == 1 ? wxB0 : 0.0f) + (sB ==  0 ? wxB1 : 0.0f);
    const float wB2 = (sB == 2 ? wxB0 : 0.0f) + (sB ==  1 ? wxB1 : 0.0f);
    const float wB3 = (sB == 3 ? wxB0 : 0.0f) + (sB ==  2 ? wxB1 : 0.0f);

    // 3-row union covers both pixels' y-taps (|YB-YA| <= 1).
    const int ymin = min(YA, YB);
    const int dA = YA - ymin;  // 0 or 1
    const int dB = YB - ymin;
    const float qA0 = (1.0f - dyA) * (float)((unsigned)YA < IMH);
    const float qA1 = dyA          * (float)((unsigned)(YA + 1) < IMH);
    const float ryA0 = (dA == 0) ? qA0 : 0.0f;
    const float ryA1 = (dA == 0) ? qA1 : qA0;
    const float ryA2 = (dA == 0) ? 0.0f : qA1;
    const float qB0 = (1.0f - dyB) * (float)((unsigned)YB < IMH);
    const float qB1 = dyB          * (float)((unsigned)(YB + 1) < IMH);
    const float ryB0 = (dB == 0) ? qB0 : 0.0f;
    const float ryB1 = (dB == 0) ? qB1 : qB0;
    const float ryB2 = (dB == 0) ? 0.0f : qB1;

    // Clamped row addresses (always in-bounds; OOB rows have zero ry weight).
    const int r0 = min(max(ymin,     0), IMH - 1);
    const int r1 = min(max(ymin + 1, 0), IMH - 1);
    const int r2 = min(max(ymin + 2, 0), IMH - 1);

    const float* img = x + (long long)b * NC * IMH * IMW;
    float* op = out + (long long)bn * NC * PIX_PER_CROP + i * WOUT + j0;

#pragma unroll
    for (int c = 0; c < NC; ++c) {
        const float* ch = img + c * (IMH * IMW);
        const F4 g0 = *reinterpret_cast<const F4*>(ch + r0 * IMW + base);
        const F4 g1 = *reinterpret_cast<const F4*>(ch + r1 * IMW + base);
        const F4 g2 = *reinterpret_cast<const F4*>(ch + r2 * IMW + base);

        const float tA0 = g0.v0 * wA0 + g0.v1 * wA1 + g0.v2 * wA2 + g0.v3 * wA3;
        const float tA1 = g1.v0 * wA0 + g1.v1 * wA1 + g1.v2 * wA2 + g1.v3 * wA3;
        const float tA2 = g2.v0 * wA0 + g2.v1 * wA1 + g2.v2 * wA2 + g2.v3 * wA3;
        const float accA = ryA0 * tA0 + ryA1 * tA1 + ryA2 * tA2;

        const float tB0 = g0.v0 * wB0 + g0.v1 * wB1 + g0.v2 * wB2 + g0.v3 * wB3;
        const float tB1 = g1.v0 * wB0 + g1.v1 * wB1 + g1.v2 * wB2 + g1.v3 * wB3;
        const float tB2 = g2.v0 * wB0 + g2.v1 * wB1 + g2.v2 * wB2 + g2.v3 * wB3;
        const float accB = ryB0 * tB0 + ryB1 * tB1 + ryB2 * tB2;

        *reinterpret_cast<F2o*>(op + c * PIX_PER_CROP) = F2o{accA, accB};
    }
}

extern "C" void kernel_launch(void* const* d_in, const int* in_sizes, int n_in,
                              void* d_out, int out_size, void* d_ws, size_t ws_size,
                              hipStream_t stream) {
    const float* x     = (const float*)d_in[0];
    const float* boxes = (const float*)d_in[1];
    float* out         = (float*)d_out;

    rot_crop_kernel<<<NBLOCKS, BLK, 0, stream>>>(x, boxes, out);
}